// Round 1
// baseline (456.584 us; speedup 1.0000x reference)
//
#include <hip/hip_runtime.h>
#include <math.h>

// ---------------------------------------------------------------------------
// CrossViewAttention (fp32 correctness-first implementation)
// B=1, C=256, S=64 (M=4096), H=32, W=128, BLOCKS=2, HEADS=8, DH=32
// Key idea: K/V projections computed over the 4096 distinct (h,w) source rows
// of grd_x ("tables"), not the 262144 gathered rows. Attention gathers table
// rows per query. All LN affines folded into GEMM A-loads where possible.
// ---------------------------------------------------------------------------

#define C_DIM 256
#define M_DIM 4096
#define W_DIM 128
#define H_DIM 32
#define NHEADS 8
#define DHEAD 32
#define ATT_SCALE 0.17677669529663687f  // 1/sqrt(32)

// ---------------- transpose grd2sat (C,M) -> x (M,C) ----------------
__global__ __launch_bounds__(256) void transpose_in(const float* __restrict__ g,
                                                    float* __restrict__ x) {
    __shared__ float tile[64][65];
    int t = threadIdx.x;
    int m0 = blockIdx.x << 6, c0 = blockIdx.y << 6;
    for (int it = 0; it < 16; ++it) {
        int idx = it * 256 + t;
        int co = idx >> 6, mo = idx & 63;
        tile[co][mo] = g[(size_t)(c0 + co) * M_DIM + m0 + mo];
    }
    __syncthreads();
    for (int it = 0; it < 16; ++it) {
        int idx = it * 256 + t;
        int mo = idx >> 6, co = idx & 63;
        x[(size_t)(m0 + mo) * C_DIM + c0 + co] = tile[co][mo];
    }
}

// ---------------- normalized grd_x columns -> yhat[(w*32+h)][c] -------------
// grd_x: (C=256, H=32, W=128); LN over C for each (h,w); no affine (folded later)
__global__ __launch_bounds__(256) void yhat_kernel(const float* __restrict__ gx,
                                                   float* __restrict__ yhat) {
    __shared__ float tile[256][33];
    __shared__ float ps[8][32];
    __shared__ float pss[8][32];
    __shared__ float mu_s[32];
    __shared__ float rs_s[32];
    int t = threadIdx.x;
    int h = blockIdx.x;            // 0..31
    int w0 = blockIdx.y << 5;      // 0,32,64,96
    int wo = t & 31, cb = t >> 5;  // 8 c-rows per pass
    for (int it = 0; it < 32; ++it) {
        int c = it * 8 + cb;
        tile[c][wo] = gx[(size_t)c * (H_DIM * W_DIM) + h * W_DIM + w0 + wo];
    }
    __syncthreads();
    {
        int w = t & 31, part = t >> 5;
        float s = 0.f, ss = 0.f;
        for (int c = part * 32; c < part * 32 + 32; ++c) {
            float x = tile[c][w];
            s += x; ss += x * x;
        }
        ps[part][w] = s; pss[part][w] = ss;
    }
    __syncthreads();
    if (t < 32) {
        float s = 0.f, ss = 0.f;
        for (int p = 0; p < 8; ++p) { s += ps[p][t]; ss += pss[p][t]; }
        float mu = s * (1.f / 256.f);
        float var = ss * (1.f / 256.f) - mu * mu;
        mu_s[t] = mu;
        rs_s[t] = rsqrtf(var + 1e-5f);
    }
    __syncthreads();
    for (int j = 0; j < 32; ++j) {
        float mu = mu_s[j], rs = rs_s[j];
        yhat[((size_t)(w0 + j) * H_DIM + h) * C_DIM + t] = (tile[t][j] - mu) * rs;
    }
}

// ---------------- row layernorm over 256, optional affine, 4 rows/block -----
template <bool AFF>
__global__ __launch_bounds__(256) void ln_rows(const float* __restrict__ X,
                                               float* __restrict__ Y,
                                               const float* __restrict__ w,
                                               const float* __restrict__ b) {
    int t = threadIdx.x;
    int wv = t >> 6, lane = t & 63;
    int m = (blockIdx.x << 2) + wv;
    float4 v = *(const float4*)&X[(size_t)m * C_DIM + (lane << 2)];
    float s = v.x + v.y + v.z + v.w;
    float ss = v.x * v.x + v.y * v.y + v.z * v.z + v.w * v.w;
#pragma unroll
    for (int o = 1; o < 64; o <<= 1) {
        s += __shfl_xor(s, o, 64);
        ss += __shfl_xor(ss, o, 64);
    }
    float mu = s * (1.f / 256.f);
    float var = ss * (1.f / 256.f) - mu * mu;
    float rs = rsqrtf(var + 1e-5f);
    float4 o4;
    if (AFF) {
        float4 w4 = *(const float4*)&w[lane << 2];
        float4 b4 = *(const float4*)&b[lane << 2];
        o4.x = (v.x - mu) * rs * w4.x + b4.x;
        o4.y = (v.y - mu) * rs * w4.y + b4.y;
        o4.z = (v.z - mu) * rs * w4.z + b4.z;
        o4.w = (v.w - mu) * rs * w4.w + b4.w;
    } else {
        o4.x = (v.x - mu) * rs;
        o4.y = (v.y - mu) * rs;
        o4.z = (v.z - mu) * rs;
        o4.w = (v.w - mu) * rs;
    }
    *(float4*)&Y[(size_t)m * C_DIM + (lane << 2)] = o4;
}

// ---------------- SGEMM: C = epi(A' @ B + bias [+ res]) --------------------
// A: MxK row-major (optionally per-column affine A' = A*aw + ab), B: KxN,
// C: MxN. BM=BN=64, BK=16, 256 threads, 4x4 per-thread microtile.
// EPI: 0=bias(optional), 1=bias+exact gelu, 2=bias+residual add
__device__ __forceinline__ float gelu_exact(float x) {
    return 0.5f * x * (1.0f + erff(x * 0.70710678118654752f));
}

template <bool AFF, int EPI>
__global__ __launch_bounds__(256) void gemm_k(const float* __restrict__ A,
                                              const float* __restrict__ B,
                                              const float* __restrict__ aw,
                                              const float* __restrict__ ab,
                                              const float* __restrict__ bias,
                                              const float* __restrict__ res,
                                              float* __restrict__ C,
                                              int M, int N, int K) {
    __shared__ float As[16][64];  // [k][m]
    __shared__ float Bs[16][64];  // [k][n]
    int t = threadIdx.x;
    int tx = t & 15, ty = t >> 4;
    int bm = blockIdx.x << 6, bn = blockIdx.y << 6;
    int ar = t >> 2, ak = (t & 3) << 2;
    int br = t >> 4, bc = (t & 15) << 2;
    const float* Ap = A + (size_t)(bm + ar) * K + ak;
    const float* Bp = B + (size_t)br * N + bn + bc;
    float acc[4][4];
#pragma unroll
    for (int j = 0; j < 4; ++j)
#pragma unroll
        for (int l = 0; l < 4; ++l) acc[j][l] = 0.f;

    for (int k0 = 0; k0 < K; k0 += 16) {
        float4 av = *(const float4*)(Ap + k0);
        float4 bv = *(const float4*)(Bp + (size_t)k0 * N);
        if (AFF) {
            float4 w4 = *(const float4*)(aw + k0 + ak);
            float4 b4 = *(const float4*)(ab + k0 + ak);
            av.x = av.x * w4.x + b4.x;
            av.y = av.y * w4.y + b4.y;
            av.z = av.z * w4.z + b4.z;
            av.w = av.w * w4.w + b4.w;
        }
        __syncthreads();
        As[ak + 0][ar] = av.x;
        As[ak + 1][ar] = av.y;
        As[ak + 2][ar] = av.z;
        As[ak + 3][ar] = av.w;
        *(float4*)&Bs[br][bc] = bv;
        __syncthreads();
#pragma unroll
        for (int kk = 0; kk < 16; ++kk) {
            const float4 a4 = *(const float4*)&As[kk][ty << 2];
            const float4 b4 = *(const float4*)&Bs[kk][tx << 2];
            acc[0][0] = fmaf(a4.x, b4.x, acc[0][0]);
            acc[0][1] = fmaf(a4.x, b4.y, acc[0][1]);
            acc[0][2] = fmaf(a4.x, b4.z, acc[0][2]);
            acc[0][3] = fmaf(a4.x, b4.w, acc[0][3]);
            acc[1][0] = fmaf(a4.y, b4.x, acc[1][0]);
            acc[1][1] = fmaf(a4.y, b4.y, acc[1][1]);
            acc[1][2] = fmaf(a4.y, b4.z, acc[1][2]);
            acc[1][3] = fmaf(a4.y, b4.w, acc[1][3]);
            acc[2][0] = fmaf(a4.z, b4.x, acc[2][0]);
            acc[2][1] = fmaf(a4.z, b4.y, acc[2][1]);
            acc[2][2] = fmaf(a4.z, b4.z, acc[2][2]);
            acc[2][3] = fmaf(a4.z, b4.w, acc[2][3]);
            acc[3][0] = fmaf(a4.w, b4.x, acc[3][0]);
            acc[3][1] = fmaf(a4.w, b4.y, acc[3][1]);
            acc[3][2] = fmaf(a4.w, b4.z, acc[3][2]);
            acc[3][3] = fmaf(a4.w, b4.w, acc[3][3]);
        }
    }
    // epilogue
    float4 bia = make_float4(0.f, 0.f, 0.f, 0.f);
    if (bias) bia = *(const float4*)&bias[bn + (tx << 2)];
#pragma unroll
    for (int j = 0; j < 4; ++j) {
        int r = bm + (ty << 2) + j;
        float4 v;
        v.x = acc[j][0] + bia.x;
        v.y = acc[j][1] + bia.y;
        v.z = acc[j][2] + bia.z;
        v.w = acc[j][3] + bia.w;
        if (EPI == 1) {
            v.x = gelu_exact(v.x);
            v.y = gelu_exact(v.y);
            v.z = gelu_exact(v.z);
            v.w = gelu_exact(v.w);
        }
        if (EPI == 2) {
            float4 rr = *(const float4*)&res[(size_t)r * N + bn + (tx << 2)];
            v.x += rr.x; v.y += rr.y; v.z += rr.z; v.w += rr.w;
        }
        *(float4*)&C[(size_t)r * N + bn + (tx << 2)] = v;
    }
}

// ---------------- attention: one wave per query m ---------------------------
// Q: (M,256); Kt/Vt: tables [(w*32+h)][256]; u: (M); A: (M,256)
__global__ __launch_bounds__(256) void attn_kernel(const float* __restrict__ Q,
                                                   const float* __restrict__ Kt,
                                                   const float* __restrict__ Vt,
                                                   const float* __restrict__ u,
                                                   float* __restrict__ A) {
    __shared__ float qs[4][256];
    __shared__ float attns[4][64];
    int t = threadIdx.x;
    int wv = t >> 6, lane = t & 63;
    int m = (blockIdx.x << 2) + wv;
    *(float4*)&qs[wv][lane << 2] = *(const float4*)&Q[(size_t)m * C_DIM + (lane << 2)];
    float uv = u[m];
    int wl = (int)floorf(uv);
    wl = max(0, min(wl, W_DIM - 1));
    int wr = min(wl + 1, W_DIM - 1);
    int hh = lane & 31, half = lane >> 5;
    int kw = half ? wr : wl;
    const float* kp = Kt + ((size_t)(kw << 5) + hh) * C_DIM;
    // output-phase mapping: lane = (half2, d)
    int d = lane & 31, half2 = lane >> 5;
    int vw = half2 ? wr : wl;
    const float* vp = Vt + ((size_t)vw << 5) * C_DIM;
    __syncthreads();
#pragma unroll 1
    for (int h = 0; h < 8; ++h) {
        // --- scores: lane <-> n
        float s = 0.f;
#pragma unroll
        for (int d4 = 0; d4 < 8; ++d4) {
            float4 kv = *(const float4*)(kp + h * 32 + (d4 << 2));
            float4 qv = *(const float4*)&qs[wv][h * 32 + (d4 << 2)];
            s = fmaf(qv.x, kv.x, s);
            s = fmaf(qv.y, kv.y, s);
            s = fmaf(qv.z, kv.z, s);
            s = fmaf(qv.w, kv.w, s);
        }
        s *= ATT_SCALE;
        float mx = s;
#pragma unroll
        for (int o = 1; o < 64; o <<= 1) mx = fmaxf(mx, __shfl_xor(mx, o, 64));
        float e = __expf(s - mx);
        float se = e;
#pragma unroll
        for (int o = 1; o < 64; o <<= 1) se += __shfl_xor(se, o, 64);
        float at = e / se;
        __syncthreads();  // previous iteration's attns reads complete
        attns[wv][lane] = at;
        __syncthreads();
        // --- output: lane <-> (half2, d); reduce over n
        float o = 0.f;
#pragma unroll 8
        for (int j = 0; j < 32; ++j) {
            o = fmaf(attns[wv][(half2 << 5) + j], vp[(size_t)j * C_DIM + h * 32 + d], o);
        }
        o += __shfl_xor(o, 32, 64);
        if (half2 == 0) A[(size_t)m * C_DIM + h * 32 + d] = o;
    }
}

// ---------------- final: L2-normalize rows, write transposed (C,M) ----------
__global__ __launch_bounds__(256) void out_kernel(const float* __restrict__ X,
                                                  float* __restrict__ out) {
    __shared__ float tile[64][65];
    __shared__ float ps[64][4];
    __shared__ float rs_s[64];
    int t = threadIdx.x;
    int m0 = blockIdx.x << 6;
    {
        int mo = t >> 2, q = t & 3;
        const float* p = X + (size_t)(m0 + mo) * C_DIM + (q << 6);
        float ss = 0.f;
        for (int c = 0; c < 64; c += 4) {
            float4 v = *(const float4*)(p + c);
            ss += v.x * v.x + v.y * v.y + v.z * v.z + v.w * v.w;
        }
        ps[mo][q] = ss;
    }
    __syncthreads();
    if (t < 64) {
        float ss = ps[t][0] + ps[t][1] + ps[t][2] + ps[t][3];
        rs_s[t] = 1.f / fmaxf(sqrtf(ss), 1e-12f);
    }
    __syncthreads();
    for (int cc = 0; cc < 4; ++cc) {
        int c0 = cc << 6;
        for (int it = 0; it < 16; ++it) {
            int idx = it * 256 + t;
            int mo = idx >> 6, co = idx & 63;
            tile[mo][co] = X[(size_t)(m0 + mo) * C_DIM + c0 + co];
        }
        __syncthreads();
        for (int it = 0; it < 16; ++it) {
            int idx = it * 256 + t;
            int co = idx >> 6, mo = idx & 63;
            out[(size_t)(c0 + co) * M_DIM + m0 + mo] = tile[mo][co] * rs_s[mo];
        }
        __syncthreads();
    }
}

// ---------------------------------------------------------------------------
extern "C" void kernel_launch(void* const* d_in, const int* in_sizes, int n_in,
                              void* d_out, int out_size, void* d_ws, size_t ws_size,
                              hipStream_t stream) {
    const float* grd2sat = (const float*)d_in[0];
    const float* grd_x   = (const float*)d_in[1];
    const float* u       = (const float*)d_in[2];
    const float* ln_q_w  = (const float*)d_in[3];
    const float* ln_q_b  = (const float*)d_in[4];
    const float* ln_k_w  = (const float*)d_in[5];
    const float* ln_k_b  = (const float*)d_in[6];
    const float* ln_v_w  = (const float*)d_in[7];
    const float* ln_v_b  = (const float*)d_in[8];
    const float* Wq      = (const float*)d_in[9];
    const float* Wk      = (const float*)d_in[10];
    const float* Wv      = (const float*)d_in[11];
    const float* Wproj   = (const float*)d_in[12];
    const float* bproj   = (const float*)d_in[13];
    const float* ln_pre_w = (const float*)d_in[14];
    const float* ln_pre_b = (const float*)d_in[15];
    const float* Wm1     = (const float*)d_in[16];
    const float* bm1     = (const float*)d_in[17];
    const float* Wm2     = (const float*)d_in[18];
    const float* bm2     = (const float*)d_in[19];
    const float* ln_post_w = (const float*)d_in[20];
    const float* ln_post_b = (const float*)d_in[21];

    float* ws   = (float*)d_ws;
    float* yhat = ws;                 // 1M floats
    float* xcur = ws + 1048576;       // 1M
    float* xhat = ws + 2097152;       // 1M (also attention output A)
    float* qbuf = ws + 3145728;       // 1M (also Z2 / next x)
    float* kbuf = ws + 4194304;       // 1M (also Z0/Z)
    float* vbuf = ws + 5242880;       // 1M
    float* hbuf = ws + 6291456;       // 2M (mlp hidden 4096x512)

    dim3 b256(256);

    transpose_in<<<dim3(64, 4), b256, 0, stream>>>(grd2sat, xcur);
    yhat_kernel<<<dim3(32, 4), b256, 0, stream>>>(grd_x, yhat);

    for (int i = 0; i < 2; ++i) {
        const float* xin = i ? (const float*)qbuf : (const float*)xcur;
        // xhat = rownorm(x) (plain)
        ln_rows<false><<<1024, b256, 0, stream>>>(xin, xhat, nullptr, nullptr);
        // Q = (xhat*lnq_w + lnq_b) @ Wq
        gemm_k<true, 0><<<dim3(64, 4), b256, 0, stream>>>(
            xhat, Wq + i * 65536, ln_q_w + i * 256, ln_q_b + i * 256,
            nullptr, nullptr, qbuf, M_DIM, 256, 256);
        // Ktab = (yhat*lnk_w + lnk_b) @ Wk ; Vtab similarly
        gemm_k<true, 0><<<dim3(64, 4), b256, 0, stream>>>(
            yhat, Wk + i * 65536, ln_k_w + i * 256, ln_k_b + i * 256,
            nullptr, nullptr, kbuf, M_DIM, 256, 256);
        gemm_k<true, 0><<<dim3(64, 4), b256, 0, stream>>>(
            yhat, Wv + i * 65536, ln_v_w + i * 256, ln_v_b + i * 256,
            nullptr, nullptr, vbuf, M_DIM, 256, 256);
        // attention -> A (reuses xhat)
        attn_kernel<<<1024, b256, 0, stream>>>(qbuf, kbuf, vbuf, u, xhat);
        // Z0 = A @ Wproj + bproj (into kbuf)
        gemm_k<false, 0><<<dim3(64, 4), b256, 0, stream>>>(
            xhat, Wproj + i * 65536, nullptr, nullptr,
            bproj + i * 256, nullptr, kbuf, M_DIM, 256, 256);
        // Z = LN_pre(Z0) in place
        ln_rows<true><<<1024, b256, 0, stream>>>(kbuf, kbuf, ln_pre_w + i * 256,
                                                 ln_pre_b + i * 256);
        // H = gelu(Z @ Wm1 + bm1)
        gemm_k<false, 1><<<dim3(64, 8), b256, 0, stream>>>(
            kbuf, Wm1 + i * 131072, nullptr, nullptr,
            bm1 + i * 512, nullptr, hbuf, M_DIM, 512, 256);
        // Z2 = Z + H @ Wm2 + bm2 (into qbuf; Q is dead)
        gemm_k<false, 2><<<dim3(64, 4), b256, 0, stream>>>(
            hbuf, Wm2 + i * 131072, nullptr, nullptr,
            bm2 + i * 256, kbuf, qbuf, M_DIM, 256, 512);
        // x_next = LN_post(Z2) in place
        ln_rows<true><<<1024, b256, 0, stream>>>(qbuf, qbuf, ln_post_w + i * 256,
                                                 ln_post_b + i * 256);
    }
    out_kernel<<<64, b256, 0, stream>>>(qbuf, (float*)d_out);
}

// Round 2
// 266.929 us; speedup vs baseline: 1.7105x; 1.7105x over previous
//
#include <hip/hip_runtime.h>
#include <math.h>

// ---------------------------------------------------------------------------
// CrossViewAttention — bf16 MFMA GEMMs + bf16 vectorized attention gather
// B=1, C=256, M=4096, W=128, H=32, BLOCKS=2, HEADS=8, DH=32
// ---------------------------------------------------------------------------

#define C_DIM 256
#define M_DIM 4096
#define W_DIM 128
#define H_DIM 32
#define ATT_SCALE 0.17677669529663687f  // 1/sqrt(32)

typedef __attribute__((ext_vector_type(8))) short short8;
typedef __attribute__((ext_vector_type(4))) short short4v;
typedef __attribute__((ext_vector_type(4))) float floatx4;

__device__ __forceinline__ unsigned short f2bf(float f) {
    unsigned u = __float_as_uint(f);
    unsigned r = (u + 0x7fffu + ((u >> 16) & 1u)) >> 16;
    return (unsigned short)r;
}
__device__ __forceinline__ float bflo(unsigned u) { return __uint_as_float(u << 16); }
__device__ __forceinline__ float bfhi(unsigned u) { return __uint_as_float(u & 0xffff0000u); }
__device__ __forceinline__ float gelu_exact(float x) {
    return 0.5f * x * (1.0f + erff(x * 0.70710678118654752f));
}

// ---------------- transpose grd2sat (C,M) -> x (M,C) ----------------
__global__ __launch_bounds__(256) void transpose_in(const float* __restrict__ g,
                                                    float* __restrict__ x) {
    __shared__ float tile[64][65];
    int t = threadIdx.x;
    int m0 = blockIdx.x << 6, c0 = blockIdx.y << 6;
    for (int it = 0; it < 16; ++it) {
        int idx = it * 256 + t;
        int co = idx >> 6, mo = idx & 63;
        tile[co][mo] = g[(size_t)(c0 + co) * M_DIM + m0 + mo];
    }
    __syncthreads();
    for (int it = 0; it < 16; ++it) {
        int idx = it * 256 + t;
        int mo = idx >> 6, co = idx & 63;
        x[(size_t)(m0 + mo) * C_DIM + c0 + co] = tile[co][mo];
    }
}

// ---------------- normalized grd_x columns -> yhat[(w*32+h)][c] -------------
__global__ __launch_bounds__(256) void yhat_kernel(const float* __restrict__ gx,
                                                   float* __restrict__ yhat) {
    __shared__ float tile[256][33];
    __shared__ float ps[8][32];
    __shared__ float pss[8][32];
    __shared__ float mu_s[32];
    __shared__ float rs_s[32];
    int t = threadIdx.x;
    int h = blockIdx.x;
    int w0 = blockIdx.y << 5;
    int wo = t & 31, cb = t >> 5;
    for (int it = 0; it < 32; ++it) {
        int c = it * 8 + cb;
        tile[c][wo] = gx[(size_t)c * (H_DIM * W_DIM) + h * W_DIM + w0 + wo];
    }
    __syncthreads();
    {
        int w = t & 31, part = t >> 5;
        float s = 0.f, ss = 0.f;
        for (int c = part * 32; c < part * 32 + 32; ++c) {
            float x = tile[c][w];
            s += x; ss += x * x;
        }
        ps[part][w] = s; pss[part][w] = ss;
    }
    __syncthreads();
    if (t < 32) {
        float s = 0.f, ss = 0.f;
        for (int p = 0; p < 8; ++p) { s += ps[p][t]; ss += pss[p][t]; }
        float mu = s * (1.f / 256.f);
        float var = ss * (1.f / 256.f) - mu * mu;
        mu_s[t] = mu;
        rs_s[t] = rsqrtf(var + 1e-5f);
    }
    __syncthreads();
    for (int j = 0; j < 32; ++j) {
        float mu = mu_s[j], rs = rs_s[j];
        yhat[((size_t)(w0 + j) * H_DIM + h) * C_DIM + t] = (tile[t][j] - mu) * rs;
    }
}

// ---------------- row layernorm over 256 with affine, 4 rows/block ----------
__global__ __launch_bounds__(256) void ln_rows(const float* __restrict__ X,
                                               float* __restrict__ Y,
                                               const float* __restrict__ w,
                                               const float* __restrict__ b) {
    int t = threadIdx.x;
    int wv = t >> 6, lane = t & 63;
    int m = (blockIdx.x << 2) + wv;
    float4 v = *(const float4*)&X[(size_t)m * C_DIM + (lane << 2)];
    float s = v.x + v.y + v.z + v.w;
    float ss = v.x * v.x + v.y * v.y + v.z * v.z + v.w * v.w;
#pragma unroll
    for (int o = 1; o < 64; o <<= 1) {
        s += __shfl_xor(s, o, 64);
        ss += __shfl_xor(ss, o, 64);
    }
    float mu = s * (1.f / 256.f);
    float var = ss * (1.f / 256.f) - mu * mu;
    float rs = rsqrtf(var + 1e-5f);
    float4 w4 = *(const float4*)&w[lane << 2];
    float4 b4 = *(const float4*)&b[lane << 2];
    float4 o4;
    o4.x = (v.x - mu) * rs * w4.x + b4.x;
    o4.y = (v.y - mu) * rs * w4.y + b4.y;
    o4.z = (v.z - mu) * rs * w4.z + b4.z;
    o4.w = (v.w - mu) * rs * w4.w + b4.w;
    *(float4*)&Y[(size_t)m * C_DIM + (lane << 2)] = o4;
}

// ---------------- batched weight transpose+convert: [R][C] f32 -> [C][R] bf16
struct WT8 {
    const float* in[8];
    unsigned short* out[8];
    int R, Cc;
};
__global__ __launch_bounds__(256) void wtrans(WT8 d) {
    __shared__ float tile[32][33];
    int wi = blockIdx.z;
    const float* in = d.in[wi];
    unsigned short* out = d.out[wi];
    int r0 = blockIdx.x << 5, c0 = blockIdx.y << 5;
    int t = threadIdx.x;
    int rl = t >> 3, cq = (t & 7) << 2;
    float4 v = *(const float4*)&in[(size_t)(r0 + rl) * d.Cc + c0 + cq];
    tile[rl][cq + 0] = v.x;
    tile[rl][cq + 1] = v.y;
    tile[rl][cq + 2] = v.z;
    tile[rl][cq + 3] = v.w;
    __syncthreads();
    int cl = t >> 3, rq = (t & 7) << 2;
    ushort4 o;
    o.x = f2bf(tile[rq + 0][cl]);
    o.y = f2bf(tile[rq + 1][cl]);
    o.z = f2bf(tile[rq + 2][cl]);
    o.w = f2bf(tile[rq + 3][cl]);
    *(ushort4*)&out[(size_t)(c0 + cl) * d.R + r0 + rq] = o;
}

// ---------------- MFMA GEMM ------------------------------------------------
// A: fp32 [M][K] (LNRM: fuse plain row-LN; AFF: fold per-k affine aw/ab)
// Bt: bf16 [N][K] (pre-transposed weights)
// OUT: 0 = fp32 [M][N]; 1 = bf16 [M][N]; 2 = bf16 transposed [N][M] (pitch M)
// EPI: 0 = bias only; 1 = bias + exact gelu; 2 = bias + residual add
// BM=32, BN=64, 256 threads (4 waves), mfma_f32_16x16x32_bf16.
template <bool LNRM, bool AFF, int EPI, int OUT>
__global__ __launch_bounds__(256) void gemm_mfma(
    const float* __restrict__ A, const unsigned short* __restrict__ Bt,
    const float* __restrict__ aw, const float* __restrict__ ab,
    const float* __restrict__ bias, const float* __restrict__ res,
    void* __restrict__ Cout, int M, int N, int K) {
    __shared__ short As[32][264];  // [m][k], pitch 264 (pad 8)
    __shared__ short Bs[64][264];  // [n][k]
    int t = threadIdx.x;
    int bm = blockIdx.x << 5, bn = blockIdx.y << 6;
    int wv = t >> 6, lane = t & 63;
    int mt = wv & 1, nt0 = (wv >> 1) << 1;
    int quad = lane >> 4, l16 = lane & 15;

    floatx4 acc0 = {0.f, 0.f, 0.f, 0.f};
    floatx4 acc1 = {0.f, 0.f, 0.f, 0.f};

    for (int kc = 0; kc < K; kc += 256) {
        if (kc) __syncthreads();
        // ---- stage A chunk: 32 rows x 256 k, fp32 -> bf16, optional LN+affine
        {
            int ar = t >> 3, cq = (t & 7) << 2;
            const float* ap = A + (size_t)(bm + ar) * K + kc + cq;
            float4 v[8];
#pragma unroll
            for (int j = 0; j < 8; ++j) v[j] = *(const float4*)(ap + j * 32);
            if (LNRM) {
                float s = 0.f, ss = 0.f;
#pragma unroll
                for (int j = 0; j < 8; ++j) {
                    s += v[j].x + v[j].y + v[j].z + v[j].w;
                    ss += v[j].x * v[j].x + v[j].y * v[j].y + v[j].z * v[j].z +
                          v[j].w * v[j].w;
                }
#pragma unroll
                for (int o = 1; o < 8; o <<= 1) {
                    s += __shfl_xor(s, o, 64);
                    ss += __shfl_xor(ss, o, 64);
                }
                float mu = s * (1.f / 256.f);
                float rs = rsqrtf(ss * (1.f / 256.f) - mu * mu + 1e-5f);
#pragma unroll
                for (int j = 0; j < 8; ++j) {
                    v[j].x = (v[j].x - mu) * rs;
                    v[j].y = (v[j].y - mu) * rs;
                    v[j].z = (v[j].z - mu) * rs;
                    v[j].w = (v[j].w - mu) * rs;
                }
            }
            if (AFF) {
#pragma unroll
                for (int j = 0; j < 8; ++j) {
                    float4 w4 = *(const float4*)(aw + kc + cq + j * 32);
                    float4 b4 = *(const float4*)(ab + kc + cq + j * 32);
                    v[j].x = v[j].x * w4.x + b4.x;
                    v[j].y = v[j].y * w4.y + b4.y;
                    v[j].z = v[j].z * w4.z + b4.z;
                    v[j].w = v[j].w * w4.w + b4.w;
                }
            }
#pragma unroll
            for (int j = 0; j < 8; ++j) {
                short4v o;
                o[0] = (short)f2bf(v[j].x);
                o[1] = (short)f2bf(v[j].y);
                o[2] = (short)f2bf(v[j].z);
                o[3] = (short)f2bf(v[j].w);
                *(short4v*)&As[ar][cq + j * 32] = o;
            }
        }
        // ---- stage B chunk: 64 rows x 256 k bf16 straight copy
        {
            int br = t >> 2, cq2 = (t & 3) << 3;
            const unsigned short* bp = Bt + (size_t)(bn + br) * K + kc + cq2;
#pragma unroll
            for (int g = 0; g < 8; ++g)
                *(short8*)&Bs[br][cq2 + g * 32] = *(const short8*)(bp + g * 32);
        }
        __syncthreads();
        // ---- MFMA over the chunk
#pragma unroll
        for (int k0 = 0; k0 < 8; ++k0) {
            short8 a = *(const short8*)&As[(mt << 4) + l16][(k0 << 5) + (quad << 3)];
            short8 b0 = *(const short8*)&Bs[(nt0 << 4) + l16][(k0 << 5) + (quad << 3)];
            short8 b1 =
                *(const short8*)&Bs[((nt0 + 1) << 4) + l16][(k0 << 5) + (quad << 3)];
            acc0 = __builtin_amdgcn_mfma_f32_16x16x32_bf16(a, b0, acc0, 0, 0, 0);
            acc1 = __builtin_amdgcn_mfma_f32_16x16x32_bf16(a, b1, acc1, 0, 0, 0);
        }
    }
    // ---- epilogue: C row = quad*4 + r, col = lane&15 (m89-verified layout)
#pragma unroll
    for (int j = 0; j < 2; ++j) {
        const floatx4 accv = j ? acc1 : acc0;
        int col = bn + ((nt0 + j) << 4) + l16;
        float bv = bias ? bias[col] : 0.f;
#pragma unroll
        for (int r = 0; r < 4; ++r) {
            int mrow = bm + (mt << 4) + (quad << 2) + r;
            float v = accv[r] + bv;
            if (EPI == 1) v = gelu_exact(v);
            if (EPI == 2) v += res[(size_t)mrow * N + col];
            if (OUT == 0)
                ((float*)Cout)[(size_t)mrow * N + col] = v;
            else if (OUT == 1)
                ((unsigned short*)Cout)[(size_t)mrow * N + col] = f2bf(v);
            else
                ((unsigned short*)Cout)[(size_t)col * M + mrow] = f2bf(v);
        }
    }
}

// ---------------- attention: one wave per query m ---------------------------
// Q fp32 [M][256]; Kt bf16 [(w*32+h)][256]; Vt bf16 transposed [256][4096]
__global__ __launch_bounds__(256) void attn_kernel(const float* __restrict__ Q,
                                                   const unsigned short* __restrict__ Kt,
                                                   const unsigned short* __restrict__ Vt,
                                                   const float* __restrict__ u,
                                                   float* __restrict__ A) {
    __shared__ float qs[4][256];
    __shared__ float attns[4][64];
    int t = threadIdx.x;
    int wv = t >> 6, lane = t & 63;
    int m = (blockIdx.x << 2) + wv;
    *(float4*)&qs[wv][lane << 2] = *(const float4*)&Q[(size_t)m * C_DIM + (lane << 2)];
    int wl = (int)floorf(u[m]);
    wl = max(0, min(wl, W_DIM - 1));
    int wr = min(wl + 1, W_DIM - 1);
    int hh = lane & 31, half = lane >> 5;
    int kw = half ? wr : wl;
    const unsigned short* kp = Kt + ((size_t)(kw << 5) + hh) * C_DIM;
    int d = lane & 31, half2 = lane >> 5;
    int vw = half2 ? wr : wl;
#pragma unroll 1
    for (int h = 0; h < 8; ++h) {
        // ---- scores: lane <-> n; 32 bf16 of K row for this head
        const unsigned short* kph = kp + h * 32;
        unsigned kk[16];
#pragma unroll
        for (int c = 0; c < 4; ++c) *(uint4*)&kk[c * 4] = *(const uint4*)(kph + c * 8);
        const float* qh = &qs[wv][h * 32];
        float s = 0.f;
#pragma unroll
        for (int j = 0; j < 16; ++j) {
            s = fmaf(bflo(kk[j]), qh[2 * j], s);
            s = fmaf(bfhi(kk[j]), qh[2 * j + 1], s);
        }
        s *= ATT_SCALE;
        float mx = s;
#pragma unroll
        for (int o = 1; o < 64; o <<= 1) mx = fmaxf(mx, __shfl_xor(mx, o, 64));
        float e = __expf(s - mx);
        float se = e;
#pragma unroll
        for (int o = 1; o < 64; o <<= 1) se += __shfl_xor(se, o, 64);
        attns[wv][lane] = e / se;  // per-wave-private LDS: no barrier needed
        // ---- output: lane <-> (half2, d); 32 contiguous bf16 of Vt row
        const unsigned short* vph = Vt + ((size_t)(h * 32 + d) << 12) + (vw << 5);
        unsigned vv[16];
#pragma unroll
        for (int c = 0; c < 4; ++c) *(uint4*)&vv[c * 4] = *(const uint4*)(vph + c * 8);
        const float* aptr = &attns[wv][half2 << 5];
        float o = 0.f;
#pragma unroll
        for (int j = 0; j < 16; ++j) {
            o = fmaf(bflo(vv[j]), aptr[2 * j], o);
            o = fmaf(bfhi(vv[j]), aptr[2 * j + 1], o);
        }
        o += __shfl_xor(o, 32, 64);
        if (half2 == 0) A[(size_t)m * C_DIM + h * 32 + d] = o;
    }
}

// ---------------- final: L2-normalize rows, write transposed (C,M) ----------
__global__ __launch_bounds__(256) void out_kernel(const float* __restrict__ X,
                                                  float* __restrict__ out) {
    __shared__ float tile[64][65];
    __shared__ float ps[64][4];
    __shared__ float rs_s[64];
    int t = threadIdx.x;
    int m0 = blockIdx.x << 6;
    {
        int mo = t >> 2, q = t & 3;
        const float* p = X + (size_t)(m0 + mo) * C_DIM + (q << 6);
        float ss = 0.f;
        for (int c = 0; c < 64; c += 4) {
            float4 v = *(const float4*)(p + c);
            ss += v.x * v.x + v.y * v.y + v.z * v.z + v.w * v.w;
        }
        ps[mo][q] = ss;
    }
    __syncthreads();
    if (t < 64) {
        float ss = ps[t][0] + ps[t][1] + ps[t][2] + ps[t][3];
        rs_s[t] = 1.f / fmaxf(sqrtf(ss), 1e-12f);
    }
    __syncthreads();
    for (int cc = 0; cc < 4; ++cc) {
        int c0 = cc << 6;
        for (int it = 0; it < 16; ++it) {
            int idx = it * 256 + t;
            int mo = idx >> 6, co = idx & 63;
            tile[mo][co] = X[(size_t)(m0 + mo) * C_DIM + c0 + co];
        }
        __syncthreads();
        for (int it = 0; it < 16; ++it) {
            int idx = it * 256 + t;
            int co = idx >> 6, mo = idx & 63;
            out[(size_t)(c0 + co) * M_DIM + m0 + mo] = tile[mo][co] * rs_s[mo];
        }
        __syncthreads();
    }
}

// ---------------------------------------------------------------------------
extern "C" void kernel_launch(void* const* d_in, const int* in_sizes, int n_in,
                              void* d_out, int out_size, void* d_ws, size_t ws_size,
                              hipStream_t stream) {
    const float* grd2sat = (const float*)d_in[0];
    const float* grd_x   = (const float*)d_in[1];
    const float* u       = (const float*)d_in[2];
    const float* ln_q_w  = (const float*)d_in[3];
    const float* ln_q_b  = (const float*)d_in[4];
    const float* ln_k_w  = (const float*)d_in[5];
    const float* ln_k_b  = (const float*)d_in[6];
    const float* ln_v_w  = (const float*)d_in[7];
    const float* ln_v_b  = (const float*)d_in[8];
    const float* Wq      = (const float*)d_in[9];
    const float* Wk      = (const float*)d_in[10];
    const float* Wv      = (const float*)d_in[11];
    const float* Wproj   = (const float*)d_in[12];
    const float* bproj   = (const float*)d_in[13];
    const float* ln_pre_w = (const float*)d_in[14];
    const float* ln_pre_b = (const float*)d_in[15];
    const float* Wm1     = (const float*)d_in[16];
    const float* bm1     = (const float*)d_in[17];
    const float* Wm2     = (const float*)d_in[18];
    const float* bm2     = (const float*)d_in[19];
    const float* ln_post_w = (const float*)d_in[20];
    const float* ln_post_b = (const float*)d_in[21];

    float* ws = (float*)d_ws;
    float* yhat = ws;                               // 4 MB
    float* xcur = ws + 1048576;                     // 4 MB (persistent x)
    float* qbuf = ws + 2097152;                     // 4 MB (Q, then Z)
    float* abuf = ws + 3145728;                     // 4 MB (attn out)
    float* hbuf = ws + 4194304;                     // 8 MB (mlp hidden 4096x512)
    unsigned short* Ktab = (unsigned short*)(ws + 6291456);  // 2 MB bf16 [4096][256]
    unsigned short* Vt   = (unsigned short*)(ws + 6815744);  // 2 MB bf16 [256][4096]
    unsigned short* Bt   = (unsigned short*)(ws + 7340032);  // 2 MB bf16 weights
    const size_t BSTRIDE = 524288;  // per-block bf16 weight stride
    const size_t OQ = 0, OK = 65536, OV = 131072, OP = 196608, OM1 = 262144,
                 OM2 = 393216;

    dim3 b256(256);

    transpose_in<<<dim3(64, 4), b256, 0, stream>>>(grd2sat, xcur);
    yhat_kernel<<<dim3(32, 4), b256, 0, stream>>>(grd_x, yhat);

    // ---- weight prep: fp32 [K][N] -> bf16 [N][K]
    {
        WT8 dA;
        const float* ins[8] = {Wq, Wq + 65536, Wk, Wk + 65536,
                               Wv, Wv + 65536, Wproj, Wproj + 65536};
        unsigned short* outs[8] = {Bt + OQ, Bt + BSTRIDE + OQ, Bt + OK,
                                   Bt + BSTRIDE + OK, Bt + OV, Bt + BSTRIDE + OV,
                                   Bt + OP, Bt + BSTRIDE + OP};
        for (int i = 0; i < 8; ++i) { dA.in[i] = ins[i]; dA.out[i] = outs[i]; }
        dA.R = 256; dA.Cc = 256;
        wtrans<<<dim3(8, 8, 8), b256, 0, stream>>>(dA);

        WT8 dB = {};
        dB.in[0] = Wm1; dB.out[0] = Bt + OM1;
        dB.in[1] = Wm1 + 131072; dB.out[1] = Bt + BSTRIDE + OM1;
        dB.R = 256; dB.Cc = 512;
        wtrans<<<dim3(8, 16, 2), b256, 0, stream>>>(dB);

        WT8 dC = {};
        dC.in[0] = Wm2; dC.out[0] = Bt + OM2;
        dC.in[1] = Wm2 + 131072; dC.out[1] = Bt + BSTRIDE + OM2;
        dC.R = 512; dC.Cc = 256;
        wtrans<<<dim3(16, 8, 2), b256, 0, stream>>>(dC);
    }

    for (int i = 0; i < 2; ++i) {
        const unsigned short* bt = Bt + i * BSTRIDE;
        // Q = LN_q(LN(x)) @ Wq   (row-LN + affine fused into A staging)
        gemm_mfma<true, true, 0, 0><<<dim3(128, 4), b256, 0, stream>>>(
            xcur, bt + OQ, ln_q_w + i * 256, ln_q_b + i * 256, nullptr, nullptr,
            qbuf, M_DIM, 256, 256);
        // Ktab (bf16) = affine_k(yhat) @ Wk
        gemm_mfma<false, true, 0, 1><<<dim3(128, 4), b256, 0, stream>>>(
            yhat, bt + OK, ln_k_w + i * 256, ln_k_b + i * 256, nullptr, nullptr,
            Ktab, M_DIM, 256, 256);
        // Vt (bf16, transposed) = affine_v(yhat) @ Wv
        gemm_mfma<false, true, 0, 2><<<dim3(128, 4), b256, 0, stream>>>(
            yhat, bt + OV, ln_v_w + i * 256, ln_v_b + i * 256, nullptr, nullptr,
            Vt, M_DIM, 256, 256);
        // attention -> abuf
        attn_kernel<<<1024, b256, 0, stream>>>(qbuf, Ktab, Vt, u, abuf);
        // Z0 = A @ Wproj + bproj  -> qbuf (Q dead)
        gemm_mfma<false, false, 0, 0><<<dim3(128, 4), b256, 0, stream>>>(
            abuf, bt + OP, nullptr, nullptr, bproj + i * 256, nullptr, qbuf,
            M_DIM, 256, 256);
        // Z = LN_pre(Z0) in place
        ln_rows<<<1024, b256, 0, stream>>>(qbuf, qbuf, ln_pre_w + i * 256,
                                           ln_pre_b + i * 256);
        // H = gelu(Z @ Wm1 + bm1)
        gemm_mfma<false, false, 1, 0><<<dim3(128, 8), b256, 0, stream>>>(
            qbuf, bt + OM1, nullptr, nullptr, bm1 + i * 512, nullptr, hbuf,
            M_DIM, 512, 256);
        // Z2 = Z + H @ Wm2 + bm2 -> xcur
        gemm_mfma<false, false, 2, 0><<<dim3(128, 4), b256, 0, stream>>>(
            hbuf, bt + OM2, nullptr, nullptr, bm2 + i * 256, qbuf, xcur,
            M_DIM, 256, 512);
        // x = LN_post(Z2) in place
        ln_rows<<<1024, b256, 0, stream>>>(xcur, xcur, ln_post_w + i * 256,
                                           ln_post_b + i * 256);
    }
    out_kernel<<<64, b256, 0, stream>>>(xcur, (float*)d_out);
}